// Round 9
// baseline (1887.378 us; speedup 1.0000x reference)
//
#include <hip/hip_runtime.h>
#include <stdint.h>

#define B_GRAPHS 2048
#define CHUNK 256                    // graphs per states chunk (8 chunks)
#define E_PER 512
#define D_USER 32
#define HID 512
#define STATES_DIM 4160              // 64*64 + 64
#define WS_NEEDED 6356992
#define MASK_HALF 4194304u           // (131072*64)/2

typedef unsigned short u16;

// ---------------- bf16 helpers (h2 compression only) ------------------------
__device__ __forceinline__ float bf2f(u16 b) {
    union { uint32_t u; float f; } c; c.u = ((uint32_t)b) << 16; return c.f;
}
__device__ __forceinline__ u16 f2bf(float f) {   // round-to-nearest-even
    union { float f; uint32_t u; } c; c.f = f;
    uint32_t u = c.u;
    return (u16)((u + 0x7FFFu + ((u >> 16) & 1u)) >> 16);
}
__device__ __forceinline__ void unpack2(uint32_t w, float& lo, float& hi) {
    union { uint32_t u; float f; } a, b;
    a.u = w << 16; b.u = w & 0xFFFF0000u;
    lo = a.f; hi = b.f;
}

// ---------------- threefry2x32, key=(0,42), PARTITIONABLE scheme ------------
__device__ __forceinline__ uint32_t rotl32(uint32_t v, int r) {
    return (v << r) | (v >> (32 - r));
}
__device__ __forceinline__ void threefry_0_42(uint32_t x0, uint32_t x1,
                                              uint32_t& o0, uint32_t& o1) {
    const uint32_t ks0 = 0u, ks1 = 42u, ks2 = 0x1BD11BDAu ^ 42u;
    x0 += ks0; x1 += ks1;
#define TFR(r) { x0 += x1; x1 = rotl32(x1, (r)); x1 ^= x0; }
    TFR(13) TFR(15) TFR(26) TFR(6)
    x0 += ks1; x1 += ks2 + 1u;
    TFR(17) TFR(29) TFR(16) TFR(24)
    x0 += ks2; x1 += ks0 + 2u;
    TFR(13) TFR(15) TFR(26) TFR(6)
    x0 += ks0; x1 += ks1 + 3u;
    TFR(17) TFR(29) TFR(16) TFR(24)
    x0 += ks1; x1 += ks2 + 4u;
    TFR(13) TFR(15) TFR(26) TFR(6)
    x0 += ks2; x1 += ks0 + 5u;
#undef TFR
    o0 = x0; o1 = x1;
}
// element j (u64 counter, j < 2^32): (w0,w1) = threefry(key, hi32=0, lo32=j)
// bits = w0 ^ w1; bernoulli(0.5) keep <=> (bits >> 31) == 0.
__device__ __forceinline__ bool keep_bit(uint32_t j) {
    uint32_t o0, o1;
    threefry_0_42(0u, j, o0, o1);
    return (((o0 ^ o1) >> 31) == 0u);
}

// ------------- diagnostics --------------------------------------------------
__global__ __launch_bounds__(256) void fill_kernel(float* __restrict__ out, float v, int n) {
    int i = blockIdx.x * 256 + threadIdx.x;
    if (i < n) out[i] = v;
}
__global__ void flag_init_kernel(float* __restrict__ flag) { flag[threadIdx.x] = 0.f; }
__global__ __launch_bounds__(256) void scan_x_kernel(const float* __restrict__ x,
                                                     float* __restrict__ flag) {
    int i0 = (blockIdx.x * 256 + threadIdx.x) * 4;
    bool bad = false;
    #pragma unroll
    for (int k = 0; k < 4; ++k) {
        float v = x[i0 + k];
        bad = bad || !(v > -1e3f && v < 1e3f);   // catches NaN/inf/huge
    }
    if (bad) flag[0] = 1.0f;
}
__global__ __launch_bounds__(256) void overlay_kernel(float* __restrict__ out,
                                                      const float* __restrict__ flag) {
    if (flag[0] != 0.0f) out[blockIdx.x * 256 + threadIdx.x] = 1.25f;
}

// ------------- per-graph: aggregate + node embed + dropout + user MLP -------
// All f32. Processes graphs [g0, g0+CHUNK); writes chunk-local states rows.
__global__ __launch_bounds__(256) void node_kernel(
    int g0,
    const float* __restrict__ x, const float* __restrict__ edge_attr,
    const float* __restrict__ user_s,
    const float* __restrict__ W_msg, const float* __restrict__ b_msg,
    const float* __restrict__ W_edge, const float* __restrict__ b_edge,
    const float* __restrict__ W_self, const float* __restrict__ b_self,
    const float* __restrict__ W1, const float* __restrict__ b1,
    const int* __restrict__ src, const int* __restrict__ dst,
    float* __restrict__ states)
{
    const int g = g0 + blockIdx.x;
    const int tid = threadIdx.x;

    __shared__ float sx[64][16];
    __shared__ float sxsum[64][16];
    __shared__ float sesum[64][2];
    __shared__ float sdeg[64];
    __shared__ float sWmsg[16][64];
    __shared__ float sWself[16][64];
    __shared__ float sWedge[2][64];
    __shared__ float sbias[64];    // b_msg + b_edge
    __shared__ float sbself[64];

    const float* xg = x + (size_t)g * 64 * 16;
    for (int i = tid; i < 1024; i += 256) {
        sx[i >> 4][i & 15] = xg[i];
        ((float*)sxsum)[i] = 0.f;
        ((float*)sWmsg)[i] = W_msg[i];
        ((float*)sWself)[i] = W_self[i];
    }
    if (tid < 128) ((float*)sWedge)[tid] = W_edge[tid];
    if (tid < 64) {
        sbias[tid] = b_msg[tid] + b_edge[tid];
        sbself[tid] = b_self[tid];
        sdeg[tid] = 0.f;
        sesum[tid][0] = 0.f; sesum[tid][1] = 0.f;
    }
    __syncthreads();

    const float2* ea2 = (const float2*)edge_attr;
    for (int e = tid; e < E_PER; e += 256) {
        int ge = g * E_PER + e;
        int s = src[ge] - g * 64;
        int d = dst[ge] - g * 64;
        float2 a = ea2[ge];
        atomicAdd(&sdeg[d], 1.0f);
        atomicAdd(&sesum[d][0], a.x);
        atomicAdd(&sesum[d][1], a.y);
        #pragma unroll
        for (int k = 0; k < 16; ++k) atomicAdd(&sxsum[d][k], sx[s][k]);
    }
    __syncthreads();

    float* out = states + (size_t)blockIdx.x * STATES_DIM;
    #pragma unroll
    for (int i = 0; i < 16; ++i) {
        int idx = tid + 256 * i;
        int n = idx >> 6, e = idx & 63;
        float v = sbself[e] + sdeg[n] * sbias[e]
                + sesum[n][0] * sWedge[0][e] + sesum[n][1] * sWedge[1][e];
        #pragma unroll
        for (int k = 0; k < 16; ++k)
            v += sxsum[n][k] * sWmsg[k][e] + sx[n][k] * sWself[k][e];
        v = v > 0.f ? v : 0.f;                         // relu
        // dropout p=0.5, flat element index = g*4096 + idx
        v = keep_bit((uint32_t)g * 4096u + (uint32_t)idx) ? v * 2.0f : 0.0f;
        out[idx] = v;
    }
    if (tid < 64) {                                    // user = relu(u @ W1 + b1)
        int e = tid;
        float v = b1[e];
        const float* us = user_s + (size_t)g * D_USER;
        #pragma unroll
        for (int k = 0; k < D_USER; ++k) v += us[k] * W1[k * 64 + e];
        out[4096 + e] = v > 0.f ? v : 0.f;
    }
}

// ------------- GEMM: C[M,N] = act(A[M,K] @ B[K,N] + bias) -------------------
// A: f32 or bf16 (AT). B, bias: f32. C: f32 or bf16 (CT).
// block tile 64x64, BK=32, 256 threads, 4x4/thread. M%64==0, N%64==0, K%32==0.
template<typename AT, typename CT, bool RELU>
__global__ __launch_bounds__(256) void gemm_any(
    const AT* __restrict__ A, const float* __restrict__ B,
    const float* __restrict__ bias, CT* __restrict__ C,
    int M, int N, int K)
{
    __shared__ float sA[32][72];   // [k][m], 288 B rows
    __shared__ float sB[32][64];   // [k][n]

    const int tid = threadIdx.x;
    const int tx = tid & 15;       // n-group
    const int ty = tid >> 4;       // m-group
    const int m0 = blockIdx.x * 64, n0 = blockIdx.y * 64;

    float acc[4][4] = {};

    for (int k0 = 0; k0 < K; k0 += 32) {
        if constexpr (sizeof(AT) == 4) {   // f32 A: transpose into sA[k][m]
            int r = tid >> 3;            // 0..31
            int c = (tid & 7) * 4;       // 0..28
            #pragma unroll
            for (int rr = 0; rr < 64; rr += 32) {
                float4 v = *(const float4*)&((const float*)A)[(size_t)(m0 + r + rr) * K + k0 + c];
                sA[c + 0][r + rr] = v.x; sA[c + 1][r + rr] = v.y;
                sA[c + 2][r + rr] = v.z; sA[c + 3][r + rr] = v.w;
            }
        } else {                           // bf16 A
            int m = tid >> 2;            // 0..63
            int c = (tid & 3) * 8;       // 0,8,16,24
            uint4 v = *(const uint4*)&((const u16*)A)[(size_t)(m0 + m) * K + k0 + c];
            unpack2(v.x, sA[c + 0][m], sA[c + 1][m]);
            unpack2(v.y, sA[c + 2][m], sA[c + 3][m]);
            unpack2(v.z, sA[c + 4][m], sA[c + 5][m]);
            unpack2(v.w, sA[c + 6][m], sA[c + 7][m]);
        }
        {   // stage B (f32): 8 floats/thread
            int r = tid >> 3;            // 0..31
            int nc = (tid & 7) * 8;      // 0..56
            float4 v0 = *(const float4*)&B[(size_t)(k0 + r) * N + n0 + nc];
            float4 v1 = *(const float4*)&B[(size_t)(k0 + r) * N + n0 + nc + 4];
            sB[r][nc + 0] = v0.x; sB[r][nc + 1] = v0.y;
            sB[r][nc + 2] = v0.z; sB[r][nc + 3] = v0.w;
            sB[r][nc + 4] = v1.x; sB[r][nc + 5] = v1.y;
            sB[r][nc + 6] = v1.z; sB[r][nc + 7] = v1.w;
        }
        __syncthreads();
        #pragma unroll
        for (int kk = 0; kk < 32; ++kk) {
            float4 av = *(const float4*)&sA[kk][ty * 4];
            float4 bv = *(const float4*)&sB[kk][tx * 4];
            float a_[4] = {av.x, av.y, av.z, av.w};
            float b_[4] = {bv.x, bv.y, bv.z, bv.w};
            #pragma unroll
            for (int i = 0; i < 4; ++i)
                #pragma unroll
                for (int j = 0; j < 4; ++j)
                    acc[i][j] += a_[i] * b_[j];
        }
        __syncthreads();
    }

    #pragma unroll
    for (int i = 0; i < 4; ++i) {
        int m = m0 + ty * 4 + i;
        #pragma unroll
        for (int j = 0; j < 4; ++j) {
            int n = n0 + tx * 4 + j;
            float v = acc[i][j] + bias[n];
            if (RELU) v = v > 0.f ? v : 0.f;
            if constexpr (sizeof(CT) == 2) C[(size_t)m * N + n] = (CT)f2bf(v);
            else                           C[(size_t)m * N + n] = (CT)v;
        }
    }
}

// ------------- softmax over the BATCH axis (axis=0), one block per column ---
__global__ __launch_bounds__(256) void softmax_kernel(
    const float* __restrict__ logits, float* __restrict__ out)
{
    const int n = blockIdx.x;      // column 0..63
    const int tid = threadIdx.x;
    __shared__ float sred[4];
    const int wid = tid >> 6, lane = tid & 63;

    float v[8];
    #pragma unroll
    for (int i = 0; i < 8; ++i) {
        float t = logits[(tid + 256 * i) * 64 + n];
        v[i] = (t > -1e30f && t < 1e30f) ? t : 0.0f;   // scrub NaN/inf
    }

    float mx = -3.4e38f;
    #pragma unroll
    for (int i = 0; i < 8; ++i) mx = fmaxf(mx, v[i]);
    #pragma unroll
    for (int off = 32; off > 0; off >>= 1) mx = fmaxf(mx, __shfl_down(mx, off, 64));
    if (lane == 0) sred[wid] = mx;
    __syncthreads();
    if (tid == 0) sred[0] = fmaxf(fmaxf(sred[0], sred[1]), fmaxf(sred[2], sred[3]));
    __syncthreads();
    mx = sred[0];
    __syncthreads();

    float sum = 0.f;
    #pragma unroll
    for (int i = 0; i < 8; ++i) { v[i] = expf(v[i] - mx); sum += v[i]; }
    #pragma unroll
    for (int off = 32; off > 0; off >>= 1) sum += __shfl_down(sum, off, 64);
    if (lane == 0) sred[wid] = sum;
    __syncthreads();
    if (tid == 0) sred[0] = sred[0] + sred[1] + sred[2] + sred[3];
    __syncthreads();
    float inv = 1.0f / sred[0];
    #pragma unroll
    for (int i = 0; i < 8; ++i) out[(tid + 256 * i) * 64 + n] = v[i] * inv;
}

// ---------------------------------------------------------------------------
extern "C" void kernel_launch(void* const* d_in, const int* in_sizes, int n_in,
                              void* d_out, int out_size, void* d_ws, size_t ws_size,
                              hipStream_t stream) {
    if (ws_size < (size_t)WS_NEEDED || n_in < 18) {
        fill_kernel<<<(out_size + 255) / 256, 256, 0, stream>>>((float*)d_out, 0.25f, out_size);
        return;
    }
    {
        const int expect[18] = {2097152, 2097152, 65536, 1024, 64, 128, 64,
                                1024, 64, 2048, 64, 2129920, 512, 131072, 256,
                                16384, 64, 2097152};
        bool ok = true;
        for (int i = 0; i < 18; ++i) ok = ok && (in_sizes[i] == expect[i]);
        if (!ok) {
            fill_kernel<<<(out_size + 255) / 256, 256, 0, stream>>>((float*)d_out, 0.125f, out_size);
            return;
        }
        if (out_size != 131072) {
            fill_kernel<<<(out_size + 255) / 256, 256, 0, stream>>>((float*)d_out, 0.0625f, out_size);
            return;
        }
    }

    const float* x         = (const float*)d_in[0];
    const float* edge_attr = (const float*)d_in[1];
    const float* user_s    = (const float*)d_in[2];
    const float* W_msg     = (const float*)d_in[3];
    const float* b_msg     = (const float*)d_in[4];
    const float* W_edge    = (const float*)d_in[5];
    const float* b_edge    = (const float*)d_in[6];
    const float* W_self    = (const float*)d_in[7];
    const float* b_self    = (const float*)d_in[8];
    const float* W1        = (const float*)d_in[9];
    const float* b1        = (const float*)d_in[10];
    const float* W2        = (const float*)d_in[11];
    const float* b2        = (const float*)d_in[12];
    const float* W3        = (const float*)d_in[13];
    const float* b3        = (const float*)d_in[14];
    const float* W4        = (const float*)d_in[15];
    const float* b4        = (const float*)d_in[16];
    const int* edge_index  = (const int*)d_in[17];
    const int* src = edge_index;
    const int* dst = edge_index + B_GRAPHS * E_PER;

    // Workspace (peak 6,356,992 B, lifetime-overlapped):
    //   states : [0,         4,259,840)  f32 CHUNK(256) x 4160 (reused x8)
    //   h3     : [0,         2,097,152)  f32 2048 x 256  (after states dead)
    //   logits : [2,097,152, 2,621,440)  f32 2048 x 64
    //   flag   : [2,621,440, 2,621,444)  f32 diagnostic (written after gemm1s)
    //   h2     : [4,259,840, 6,356,992)  bf16 2048 x 512
    char* ws = (char*)d_ws;
    float* states = (float*)ws;
    float* h3     = (float*)ws;
    float* logits = (float*)(ws + 2097152);
    float* flag   = (float*)(ws + 2621440);
    u16*   h2     = (u16*)  (ws + 4259840);

    for (int c = 0; c < B_GRAPHS / CHUNK; ++c) {
        node_kernel<<<CHUNK, 256, 0, stream>>>(
            c * CHUNK, x, edge_attr, user_s, W_msg, b_msg, W_edge, b_edge,
            W_self, b_self, W1, b1, src, dst, states);
        gemm_any<float, u16, true><<<dim3(CHUNK / 64, HID / 64), 256, 0, stream>>>(
            states, W2, b2, h2 + (size_t)c * CHUNK * HID, CHUNK, HID, STATES_DIM);
    }

    gemm_any<u16,   float, true ><<<dim3(32, 4), 256, 0, stream>>>(h2, W3, b3, h3,
                                                                   B_GRAPHS, HID / 2, HID);
    gemm_any<float, float, false><<<dim3(32, 1), 256, 0, stream>>>(h3, W4, b4, logits,
                                                                   B_GRAPHS, 64, HID / 2);

    softmax_kernel<<<64, 256, 0, stream>>>(logits, (float*)d_out);

    // dtype tripwire: if x is not sane f32, stamp 1.25 over the output
    flag_init_kernel<<<1, 64, 0, stream>>>(flag);
    scan_x_kernel<<<2048, 256, 0, stream>>>(x, flag);
    overlay_kernel<<<512, 256, 0, stream>>>((float*)d_out, flag);
}

// Round 10
// 330.433 us; speedup vs baseline: 5.7118x; 5.7118x over previous
//
#include <hip/hip_runtime.h>
#include <stdint.h>

#define B_GRAPHS 2048
#define CHUNK 256                    // fallback path: graphs per chunk
#define E_PER 512
#define D_USER 32
#define HID 512
#define GK 4160                      // states dim = 64*64 + 64
#define STATES_DIM 4160
#define WS_FALLBACK 6356992
#define WS_FAST 23396352

typedef unsigned short u16;
typedef __attribute__((ext_vector_type(8))) short short8;   // 8 bf16 (4 VGPRs)
typedef __attribute__((ext_vector_type(4))) float f32x4;    // MFMA accumulator

// ---------------- bf16 helpers ----------------------------------------------
__device__ __forceinline__ float bf2f(u16 b) {
    union { uint32_t u; float f; } c; c.u = ((uint32_t)b) << 16; return c.f;
}
__device__ __forceinline__ u16 f2bf(float f) {   // round-to-nearest-even
    union { float f; uint32_t u; } c; c.f = f;
    uint32_t u = c.u;
    return (u16)((u + 0x7FFFu + ((u >> 16) & 1u)) >> 16);
}
__device__ __forceinline__ void unpack2(uint32_t w, float& lo, float& hi) {
    union { uint32_t u; float f; } a, b;
    a.u = w << 16; b.u = w & 0xFFFF0000u;
    lo = a.f; hi = b.f;
}

// ---------------- threefry2x32, key=(0,42), partitionable (proven R9) -------
__device__ __forceinline__ uint32_t rotl32(uint32_t v, int r) {
    return (v << r) | (v >> (32 - r));
}
__device__ __forceinline__ void threefry_0_42(uint32_t x0, uint32_t x1,
                                              uint32_t& o0, uint32_t& o1) {
    const uint32_t ks0 = 0u, ks1 = 42u, ks2 = 0x1BD11BDAu ^ 42u;
    x0 += ks0; x1 += ks1;
#define TFR(r) { x0 += x1; x1 = rotl32(x1, (r)); x1 ^= x0; }
    TFR(13) TFR(15) TFR(26) TFR(6)
    x0 += ks1; x1 += ks2 + 1u;
    TFR(17) TFR(29) TFR(16) TFR(24)
    x0 += ks2; x1 += ks0 + 2u;
    TFR(13) TFR(15) TFR(26) TFR(6)
    x0 += ks0; x1 += ks1 + 3u;
    TFR(17) TFR(29) TFR(16) TFR(24)
    x0 += ks1; x1 += ks2 + 4u;
    TFR(13) TFR(15) TFR(26) TFR(6)
    x0 += ks2; x1 += ks0 + 5u;
#undef TFR
    o0 = x0; o1 = x1;
}
__device__ __forceinline__ bool keep_bit(uint32_t j) {
    uint32_t o0, o1;
    threefry_0_42(0u, j, o0, o1);
    return (((o0 ^ o1) >> 31) == 0u);
}

// ------------- diagnostic fill ----------------------------------------------
__global__ __launch_bounds__(256) void fill_kernel(float* __restrict__ out, float v, int n) {
    int i = blockIdx.x * 256 + threadIdx.x;
    if (i < n) out[i] = v;
}

// ------------- per-graph: aggregate + node embed + dropout + user MLP -------
// OT = u16 (bf16 states, fast path) or float (fallback). Graph g = g0+blockIdx.
template<typename OT>
__global__ __launch_bounds__(256) void node_kernel(
    int g0,
    const float* __restrict__ x, const float* __restrict__ edge_attr,
    const float* __restrict__ user_s,
    const float* __restrict__ W_msg, const float* __restrict__ b_msg,
    const float* __restrict__ W_edge, const float* __restrict__ b_edge,
    const float* __restrict__ W_self, const float* __restrict__ b_self,
    const float* __restrict__ W1, const float* __restrict__ b1,
    const int* __restrict__ src, const int* __restrict__ dst,
    OT* __restrict__ states)
{
    const int g = g0 + blockIdx.x;
    const int tid = threadIdx.x;

    __shared__ float sx[64][16];
    __shared__ float sxsum[64][16];
    __shared__ float sesum[64][2];
    __shared__ float sdeg[64];
    __shared__ float sWmsg[16][64];
    __shared__ float sWself[16][64];
    __shared__ float sWedge[2][64];
    __shared__ float sbias[64];    // b_msg + b_edge
    __shared__ float sbself[64];

    const float* xg = x + (size_t)g * 64 * 16;
    for (int i = tid; i < 1024; i += 256) {
        sx[i >> 4][i & 15] = xg[i];
        ((float*)sxsum)[i] = 0.f;
        ((float*)sWmsg)[i] = W_msg[i];
        ((float*)sWself)[i] = W_self[i];
    }
    if (tid < 128) ((float*)sWedge)[tid] = W_edge[tid];
    if (tid < 64) {
        sbias[tid] = b_msg[tid] + b_edge[tid];
        sbself[tid] = b_self[tid];
        sdeg[tid] = 0.f;
        sesum[tid][0] = 0.f; sesum[tid][1] = 0.f;
    }
    __syncthreads();

    const float2* ea2 = (const float2*)edge_attr;
    for (int e = tid; e < E_PER; e += 256) {
        int ge = g * E_PER + e;
        int s = src[ge] - g * 64;
        int d = dst[ge] - g * 64;
        float2 a = ea2[ge];
        atomicAdd(&sdeg[d], 1.0f);
        atomicAdd(&sesum[d][0], a.x);
        atomicAdd(&sesum[d][1], a.y);
        #pragma unroll
        for (int k = 0; k < 16; ++k) atomicAdd(&sxsum[d][k], sx[s][k]);
    }
    __syncthreads();

    OT* out = states + (size_t)blockIdx.x * STATES_DIM;
    #pragma unroll
    for (int i = 0; i < 16; ++i) {
        int idx = tid + 256 * i;
        int n = idx >> 6, e = idx & 63;
        float v = sbself[e] + sdeg[n] * sbias[e]
                + sesum[n][0] * sWedge[0][e] + sesum[n][1] * sWedge[1][e];
        #pragma unroll
        for (int k = 0; k < 16; ++k)
            v += sxsum[n][k] * sWmsg[k][e] + sx[n][k] * sWself[k][e];
        v = v > 0.f ? v : 0.f;                         // relu
        v = keep_bit((uint32_t)g * 4096u + (uint32_t)idx) ? v * 2.0f : 0.0f;
        if constexpr (sizeof(OT) == 2) out[idx] = f2bf(v);
        else                           out[idx] = v;
    }
    if (tid < 64) {                                    // user = relu(u @ W1 + b1)
        int e = tid;
        float v = b1[e];
        const float* us = user_s + (size_t)g * D_USER;
        #pragma unroll
        for (int k = 0; k < D_USER; ++k) v += us[k] * W1[k * 64 + e];
        v = v > 0.f ? v : 0.f;
        if constexpr (sizeof(OT) == 2) out[4096 + e] = f2bf(v);
        else                           out[4096 + e] = v;
    }
}

// ------------- W2 [4160,512] f32 -> W2T [512,4160] bf16 ---------------------
__global__ __launch_bounds__(256) void transpose_w2(const float* __restrict__ W2,
                                                    u16* __restrict__ W2T) {
    __shared__ float sT[32][33];
    const int k0 = blockIdx.x * 32, n0 = blockIdx.y * 32;
    const int tr = threadIdx.x >> 5, tc = threadIdx.x & 31;
    #pragma unroll
    for (int i = 0; i < 32; i += 8)
        sT[tr + i][tc] = W2[(size_t)(k0 + tr + i) * 512 + n0 + tc];
    __syncthreads();
    #pragma unroll
    for (int i = 0; i < 32; i += 8)
        W2T[(size_t)(n0 + tr + i) * GK + k0 + tc] = f2bf(sT[tc][tr + i]);
}

// ------------- gemm1 MFMA: h2 = relu(states @ W2 + b2), bf16 in, bf16 out ---
// A: states bf16 [2048][4160]; BT: W2T bf16 [512][4160]; C: h2 bf16 [2048][512]
// Block 256 thr (4 waves), tile 64x64, BK=32; wave -> 32x32 quadrant,
// 2x2 of v_mfma_f32_16x16x32_bf16.
// Layouts (learn_hip-verified): A: m=lane&15, k=quad*8+j; B: n=lane&15,
// k=quad*8+j; C/D: col=lane&15, row=quad*4+reg.
__global__ __launch_bounds__(256) void gemm1_mfma(
    const u16* __restrict__ A, const u16* __restrict__ BT,
    const float* __restrict__ bias, u16* __restrict__ C)
{
    __shared__ u16 sA[64][40];     // 80 B rows: 16B-aligned frags, 2-way banks
    __shared__ u16 sB[64][40];

    const int tid = threadIdx.x;
    const int m0 = blockIdx.x * 64, n0 = blockIdx.y * 64;
    const int wave = tid >> 6, lane = tid & 63;
    const int wm = (wave >> 1) * 32, wn = (wave & 1) * 32;
    const int lm = lane & 15, q = lane >> 4;

    f32x4 acc[2][2];
    #pragma unroll
    for (int i = 0; i < 2; ++i)
        #pragma unroll
        for (int j = 0; j < 2; ++j)
            #pragma unroll
            for (int r = 0; r < 4; ++r) acc[i][j][r] = 0.f;

    const int row = tid >> 2;          // 0..63
    const int seg = (tid & 3) * 8;     // 0,8,16,24

    for (int k0 = 0; k0 < GK; k0 += 32) {
        *(uint4*)&sA[row][seg] = *(const uint4*)&A[(size_t)(m0 + row) * GK + k0 + seg];
        *(uint4*)&sB[row][seg] = *(const uint4*)&BT[(size_t)(n0 + row) * GK + k0 + seg];
        __syncthreads();
        short8 a0 = *(const short8*)&sA[wm + lm][q * 8];
        short8 a1 = *(const short8*)&sA[wm + 16 + lm][q * 8];
        short8 b0 = *(const short8*)&sB[wn + lm][q * 8];
        short8 b1 = *(const short8*)&sB[wn + 16 + lm][q * 8];
        acc[0][0] = __builtin_amdgcn_mfma_f32_16x16x32_bf16(a0, b0, acc[0][0], 0, 0, 0);
        acc[0][1] = __builtin_amdgcn_mfma_f32_16x16x32_bf16(a0, b1, acc[0][1], 0, 0, 0);
        acc[1][0] = __builtin_amdgcn_mfma_f32_16x16x32_bf16(a1, b0, acc[1][0], 0, 0, 0);
        acc[1][1] = __builtin_amdgcn_mfma_f32_16x16x32_bf16(a1, b1, acc[1][1], 0, 0, 0);
        __syncthreads();
    }

    #pragma unroll
    for (int mi = 0; mi < 2; ++mi)
        #pragma unroll
        for (int ni = 0; ni < 2; ++ni)
            #pragma unroll
            for (int r = 0; r < 4; ++r) {
                int m = m0 + wm + mi * 16 + q * 4 + r;
                int n = n0 + wn + ni * 16 + lm;
                float v = acc[mi][ni][r] + bias[n];
                v = v > 0.f ? v : 0.f;
                C[(size_t)m * 512 + n] = f2bf(v);
            }
}

// ------------- f32 GEMM (proven R9): C = act(A @ B + bias) ------------------
template<typename AT, typename CT, bool RELU>
__global__ __launch_bounds__(256) void gemm_any(
    const AT* __restrict__ A, const float* __restrict__ B,
    const float* __restrict__ bias, CT* __restrict__ C,
    int M, int N, int K)
{
    __shared__ float sA[32][72];
    __shared__ float sB[32][64];

    const int tid = threadIdx.x;
    const int tx = tid & 15;
    const int ty = tid >> 4;
    const int m0 = blockIdx.x * 64, n0 = blockIdx.y * 64;

    float acc[4][4] = {};

    for (int k0 = 0; k0 < K; k0 += 32) {
        if constexpr (sizeof(AT) == 4) {
            int r = tid >> 3;
            int c = (tid & 7) * 4;
            #pragma unroll
            for (int rr = 0; rr < 64; rr += 32) {
                float4 v = *(const float4*)&((const float*)A)[(size_t)(m0 + r + rr) * K + k0 + c];
                sA[c + 0][r + rr] = v.x; sA[c + 1][r + rr] = v.y;
                sA[c + 2][r + rr] = v.z; sA[c + 3][r + rr] = v.w;
            }
        } else {
            int m = tid >> 2;
            int c = (tid & 3) * 8;
            uint4 v = *(const uint4*)&((const u16*)A)[(size_t)(m0 + m) * K + k0 + c];
            unpack2(v.x, sA[c + 0][m], sA[c + 1][m]);
            unpack2(v.y, sA[c + 2][m], sA[c + 3][m]);
            unpack2(v.z, sA[c + 4][m], sA[c + 5][m]);
            unpack2(v.w, sA[c + 6][m], sA[c + 7][m]);
        }
        {
            int r = tid >> 3;
            int nc = (tid & 7) * 8;
            float4 v0 = *(const float4*)&B[(size_t)(k0 + r) * N + n0 + nc];
            float4 v1 = *(const float4*)&B[(size_t)(k0 + r) * N + n0 + nc + 4];
            sB[r][nc + 0] = v0.x; sB[r][nc + 1] = v0.y;
            sB[r][nc + 2] = v0.z; sB[r][nc + 3] = v0.w;
            sB[r][nc + 4] = v1.x; sB[r][nc + 5] = v1.y;
            sB[r][nc + 6] = v1.z; sB[r][nc + 7] = v1.w;
        }
        __syncthreads();
        #pragma unroll
        for (int kk = 0; kk < 32; ++kk) {
            float4 av = *(const float4*)&sA[kk][ty * 4];
            float4 bv = *(const float4*)&sB[kk][tx * 4];
            float a_[4] = {av.x, av.y, av.z, av.w};
            float b_[4] = {bv.x, bv.y, bv.z, bv.w};
            #pragma unroll
            for (int i = 0; i < 4; ++i)
                #pragma unroll
                for (int j = 0; j < 4; ++j)
                    acc[i][j] += a_[i] * b_[j];
        }
        __syncthreads();
    }

    #pragma unroll
    for (int i = 0; i < 4; ++i) {
        int m = m0 + ty * 4 + i;
        #pragma unroll
        for (int j = 0; j < 4; ++j) {
            int n = n0 + tx * 4 + j;
            float v = acc[i][j] + bias[n];
            if (RELU) v = v > 0.f ? v : 0.f;
            if constexpr (sizeof(CT) == 2) C[(size_t)m * N + n] = (CT)f2bf(v);
            else                           C[(size_t)m * N + n] = (CT)v;
        }
    }
}

// ------------- softmax over axis 0, in-place capable ------------------------
__global__ __launch_bounds__(256) void softmax_kernel(
    const float* __restrict__ logits, float* __restrict__ out)
{
    const int n = blockIdx.x;
    const int tid = threadIdx.x;
    __shared__ float sred[4];
    const int wid = tid >> 6, lane = tid & 63;

    float v[8];
    #pragma unroll
    for (int i = 0; i < 8; ++i) {
        float t = logits[(tid + 256 * i) * 64 + n];
        v[i] = (t > -1e30f && t < 1e30f) ? t : 0.0f;   // scrub NaN/inf
    }

    float mx = -3.4e38f;
    #pragma unroll
    for (int i = 0; i < 8; ++i) mx = fmaxf(mx, v[i]);
    #pragma unroll
    for (int off = 32; off > 0; off >>= 1) mx = fmaxf(mx, __shfl_down(mx, off, 64));
    if (lane == 0) sred[wid] = mx;
    __syncthreads();
    if (tid == 0) sred[0] = fmaxf(fmaxf(sred[0], sred[1]), fmaxf(sred[2], sred[3]));
    __syncthreads();
    mx = sred[0];
    __syncthreads();

    float sum = 0.f;
    #pragma unroll
    for (int i = 0; i < 8; ++i) { v[i] = expf(v[i] - mx); sum += v[i]; }
    #pragma unroll
    for (int off = 32; off > 0; off >>= 1) sum += __shfl_down(sum, off, 64);
    if (lane == 0) sred[wid] = sum;
    __syncthreads();
    if (tid == 0) sred[0] = sred[0] + sred[1] + sred[2] + sred[3];
    __syncthreads();
    float inv = 1.0f / sred[0];
    #pragma unroll
    for (int i = 0; i < 8; ++i) out[(tid + 256 * i) * 64 + n] = v[i] * inv;
}

// ---------------------------------------------------------------------------
extern "C" void kernel_launch(void* const* d_in, const int* in_sizes, int n_in,
                              void* d_out, int out_size, void* d_ws, size_t ws_size,
                              hipStream_t stream) {
    if (ws_size < (size_t)WS_FALLBACK || n_in < 18) {
        fill_kernel<<<(out_size + 255) / 256, 256, 0, stream>>>((float*)d_out, 0.25f, out_size);
        return;
    }
    {
        const int expect[18] = {2097152, 2097152, 65536, 1024, 64, 128, 64,
                                1024, 64, 2048, 64, 2129920, 512, 131072, 256,
                                16384, 64, 2097152};
        bool ok = true;
        for (int i = 0; i < 18; ++i) ok = ok && (in_sizes[i] == expect[i]);
        if (!ok || out_size != 131072) {
            fill_kernel<<<(out_size + 255) / 256, 256, 0, stream>>>((float*)d_out, 0.125f, out_size);
            return;
        }
    }

    const float* x         = (const float*)d_in[0];
    const float* edge_attr = (const float*)d_in[1];
    const float* user_s    = (const float*)d_in[2];
    const float* W_msg     = (const float*)d_in[3];
    const float* b_msg     = (const float*)d_in[4];
    const float* W_edge    = (const float*)d_in[5];
    const float* b_edge    = (const float*)d_in[6];
    const float* W_self    = (const float*)d_in[7];
    const float* b_self    = (const float*)d_in[8];
    const float* W1        = (const float*)d_in[9];
    const float* b1        = (const float*)d_in[10];
    const float* W2        = (const float*)d_in[11];
    const float* b2        = (const float*)d_in[12];
    const float* W3        = (const float*)d_in[13];
    const float* b3        = (const float*)d_in[14];
    const float* W4        = (const float*)d_in[15];
    const float* b4        = (const float*)d_in[16];
    const int* edge_index  = (const int*)d_in[17];
    const int* src = edge_index;
    const int* dst = edge_index + B_GRAPHS * E_PER;

    float* logits = (float*)d_out;     // gemm3 -> d_out, softmax in-place
    char* ws = (char*)d_ws;

    if (ws_size >= (size_t)WS_FAST) {
        // FAST path layout:
        //   states bf16 : [0,          17,039,360)
        //   W2T bf16    : [17,039,360, 21,299,200)
        //   h2 bf16     : [21,299,200, 23,396,352)
        //   h3 f32      : [0,           2,097,152)   (overlay; states dead)
        u16*   states = (u16*)ws;
        u16*   W2T    = (u16*)(ws + 17039360);
        u16*   h2     = (u16*)(ws + 21299200);
        float* h3     = (float*)ws;

        transpose_w2<<<dim3(130, 16), 256, 0, stream>>>(W2, W2T);
        node_kernel<u16><<<B_GRAPHS, 256, 0, stream>>>(
            0, x, edge_attr, user_s, W_msg, b_msg, W_edge, b_edge,
            W_self, b_self, W1, b1, src, dst, states);
        gemm1_mfma<<<dim3(32, 8), 256, 0, stream>>>(states, W2T, b2, h2);
        gemm_any<u16,   float, true ><<<dim3(32, 4), 256, 0, stream>>>(
            h2, W3, b3, h3, B_GRAPHS, HID / 2, HID);
        gemm_any<float, float, false><<<dim3(32, 1), 256, 0, stream>>>(
            h3, W4, b4, logits, B_GRAPHS, 64, HID / 2);
        softmax_kernel<<<64, 256, 0, stream>>>(logits, logits);
    } else {
        // FALLBACK (proven R9) layout:
        //   states f32 : [0, 4,259,840)   (CHUNK x 4160, reused x8)
        //   h3 f32     : [0, 2,097,152)   (overlay; states dead)
        //   h2 bf16    : [4,259,840, 6,356,992)
        float* states = (float*)ws;
        float* h3     = (float*)ws;
        u16*   h2     = (u16*)(ws + 4259840);

        for (int c = 0; c < B_GRAPHS / CHUNK; ++c) {
            node_kernel<float><<<CHUNK, 256, 0, stream>>>(
                c * CHUNK, x, edge_attr, user_s, W_msg, b_msg, W_edge, b_edge,
                W_self, b_self, W1, b1, src, dst, states);
            gemm_any<float, u16, true><<<dim3(CHUNK / 64, HID / 64), 256, 0, stream>>>(
                states, W2, b2, h2 + (size_t)c * CHUNK * HID, CHUNK, HID, STATES_DIM);
        }
        gemm_any<u16,   float, true ><<<dim3(32, 4), 256, 0, stream>>>(
            h2, W3, b3, h3, B_GRAPHS, HID / 2, HID);
        gemm_any<float, float, false><<<dim3(32, 1), 256, 0, stream>>>(
            h3, W4, b4, logits, B_GRAPHS, 64, HID / 2);
        softmax_kernel<<<64, 256, 0, stream>>>(logits, logits);
    }
}

// Round 11
// 318.325 us; speedup vs baseline: 5.9291x; 1.0380x over previous
//
#include <hip/hip_runtime.h>
#include <stdint.h>

#define B_GRAPHS 2048
#define CHUNK 256                    // fallback path: graphs per chunk
#define E_PER 512
#define D_USER 32
#define HID 512
#define GK 4160                      // states dim = 64*64 + 64
#define STATES_DIM 4160
#define WS_FALLBACK 6356992
#define WS_FAST 23396352

typedef unsigned short u16;
typedef __attribute__((ext_vector_type(8))) short short8;   // 8 bf16 (4 VGPRs)
typedef __attribute__((ext_vector_type(4))) float f32x4;    // MFMA accumulator

// ---------------- bf16 helpers ----------------------------------------------
__device__ __forceinline__ float bf2f(u16 b) {
    union { uint32_t u; float f; } c; c.u = ((uint32_t)b) << 16; return c.f;
}
__device__ __forceinline__ u16 f2bf(float f) {   // round-to-nearest-even
    union { float f; uint32_t u; } c; c.f = f;
    uint32_t u = c.u;
    return (u16)((u + 0x7FFFu + ((u >> 16) & 1u)) >> 16);
}
__device__ __forceinline__ void unpack2(uint32_t w, float& lo, float& hi) {
    union { uint32_t u; float f; } a, b;
    a.u = w << 16; b.u = w & 0xFFFF0000u;
    lo = a.f; hi = b.f;
}

// ---------------- threefry2x32, key=(0,42), partitionable (proven R9) -------
__device__ __forceinline__ uint32_t rotl32(uint32_t v, int r) {
    return (v << r) | (v >> (32 - r));
}
__device__ __forceinline__ void threefry_0_42(uint32_t x0, uint32_t x1,
                                              uint32_t& o0, uint32_t& o1) {
    const uint32_t ks0 = 0u, ks1 = 42u, ks2 = 0x1BD11BDAu ^ 42u;
    x0 += ks0; x1 += ks1;
#define TFR(r) { x0 += x1; x1 = rotl32(x1, (r)); x1 ^= x0; }
    TFR(13) TFR(15) TFR(26) TFR(6)
    x0 += ks1; x1 += ks2 + 1u;
    TFR(17) TFR(29) TFR(16) TFR(24)
    x0 += ks2; x1 += ks0 + 2u;
    TFR(13) TFR(15) TFR(26) TFR(6)
    x0 += ks0; x1 += ks1 + 3u;
    TFR(17) TFR(29) TFR(16) TFR(24)
    x0 += ks1; x1 += ks2 + 4u;
    TFR(13) TFR(15) TFR(26) TFR(6)
    x0 += ks2; x1 += ks0 + 5u;
#undef TFR
    o0 = x0; o1 = x1;
}
__device__ __forceinline__ bool keep_bit(uint32_t j) {
    uint32_t o0, o1;
    threefry_0_42(0u, j, o0, o1);
    return (((o0 ^ o1) >> 31) == 0u);
}

// ------------- mask kernel: 64 keep-bits per u64 word -----------------------
// element j: bit j&63 of mask[j>>6]; matches node_fast's (mask[g*64+n]>>lane)&1
__global__ __launch_bounds__(256) void mask_kernel(unsigned long long* __restrict__ mask) {
    uint32_t j = blockIdx.x * 256u + threadIdx.x;    // 0 .. 8388607
    uint32_t o0, o1;
    threefry_0_42(0u, j, o0, o1);
    unsigned long long b = __ballot(((o0 ^ o1) >> 31) == 0u);
    if ((threadIdx.x & 63u) == 0u) mask[j >> 6] = b;
}

// ------------- diagnostic fill ----------------------------------------------
__global__ __launch_bounds__(256) void fill_kernel(float* __restrict__ out, float v, int n) {
    int i = blockIdx.x * 256 + threadIdx.x;
    if (i < n) out[i] = v;
}

// ------------- FAST node kernel: agg + embed + dropout + user MLP -----------
// One block per graph. Wave-uniform node per epilogue iteration; weights in
// registers (column = lane); mask precomputed.
__global__ __launch_bounds__(256) void node_fast(
    const float* __restrict__ x, const float* __restrict__ edge_attr,
    const float* __restrict__ user_s,
    const float* __restrict__ W_msg, const float* __restrict__ b_msg,
    const float* __restrict__ W_edge, const float* __restrict__ b_edge,
    const float* __restrict__ W_self, const float* __restrict__ b_self,
    const float* __restrict__ W1, const float* __restrict__ b1,
    const int* __restrict__ src, const int* __restrict__ dst,
    const unsigned long long* __restrict__ mask,
    u16* __restrict__ states)
{
    const int g = blockIdx.x;
    const int tid = threadIdx.x;
    const int w = tid >> 6, lane = tid & 63;

    __shared__ float sx[64][16];
    __shared__ float sxsum[64][16];
    __shared__ float sesum[64][2];
    __shared__ float sdeg[64];

    // per-lane weight columns in registers (coalesced loads)
    float rWmsg[16], rWself[16];
    #pragma unroll
    for (int k = 0; k < 16; ++k) {
        rWmsg[k]  = W_msg[k * 64 + lane];
        rWself[k] = W_self[k * 64 + lane];
    }
    const float rWe0   = W_edge[lane];
    const float rWe1   = W_edge[64 + lane];
    const float rbias  = b_msg[lane] + b_edge[lane];
    const float rbself = b_self[lane];

    const float* xg = x + (size_t)g * 1024;
    for (int i = tid; i < 1024; i += 256) {
        ((float*)sx)[i] = xg[i];
        ((float*)sxsum)[i] = 0.f;
    }
    if (tid < 64) { sdeg[tid] = 0.f; sesum[tid][0] = 0.f; sesum[tid][1] = 0.f; }
    __syncthreads();

    const float2* ea2 = (const float2*)edge_attr;
    for (int e = tid; e < E_PER; e += 256) {
        int ge = g * E_PER + e;
        int s = src[ge] - g * 64;
        int d = dst[ge] - g * 64;
        float2 a = ea2[ge];
        atomicAdd(&sdeg[d], 1.0f);
        atomicAdd(&sesum[d][0], a.x);
        atomicAdd(&sesum[d][1], a.y);
        #pragma unroll
        for (int k = 0; k < 16; ++k) atomicAdd(&sxsum[d][k], sx[s][k]);
    }
    __syncthreads();

    u16* out = states + (size_t)g * STATES_DIM;
    #pragma unroll
    for (int i = 0; i < 16; ++i) {
        const int n = 4 * i + w;                       // wave-uniform node
        float v = rbself + sdeg[n] * rbias
                + sesum[n][0] * rWe0 + sesum[n][1] * rWe1;
        float4 s0 = *(const float4*)&sxsum[n][0];
        float4 s1 = *(const float4*)&sxsum[n][4];
        float4 s2 = *(const float4*)&sxsum[n][8];
        float4 s3 = *(const float4*)&sxsum[n][12];
        float4 x0 = *(const float4*)&sx[n][0];
        float4 x1 = *(const float4*)&sx[n][4];
        float4 x2 = *(const float4*)&sx[n][8];
        float4 x3 = *(const float4*)&sx[n][12];
        v += s0.x*rWmsg[0]  + s0.y*rWmsg[1]  + s0.z*rWmsg[2]  + s0.w*rWmsg[3]
           + s1.x*rWmsg[4]  + s1.y*rWmsg[5]  + s1.z*rWmsg[6]  + s1.w*rWmsg[7]
           + s2.x*rWmsg[8]  + s2.y*rWmsg[9]  + s2.z*rWmsg[10] + s2.w*rWmsg[11]
           + s3.x*rWmsg[12] + s3.y*rWmsg[13] + s3.z*rWmsg[14] + s3.w*rWmsg[15]
           + x0.x*rWself[0]  + x0.y*rWself[1]  + x0.z*rWself[2]  + x0.w*rWself[3]
           + x1.x*rWself[4]  + x1.y*rWself[5]  + x1.z*rWself[6]  + x1.w*rWself[7]
           + x2.x*rWself[8]  + x2.y*rWself[9]  + x2.z*rWself[10] + x2.w*rWself[11]
           + x3.x*rWself[12] + x3.y*rWself[13] + x3.z*rWself[14] + x3.w*rWself[15];
        v = v > 0.f ? v : 0.f;                         // relu
        unsigned long long m = mask[g * 64 + n];       // broadcast load
        v = ((m >> lane) & 1ull) ? v * 2.0f : 0.0f;    // dropout p=0.5
        out[n * 64 + lane] = f2bf(v);
    }
    if (tid < 64) {                                    // user = relu(u @ W1 + b1)
        float v = b1[tid];
        const float* us = user_s + (size_t)g * D_USER;
        #pragma unroll
        for (int k = 0; k < D_USER; ++k) v += us[k] * W1[k * 64 + tid];
        out[4096 + tid] = f2bf(v > 0.f ? v : 0.f);
    }
}

// ------------- FALLBACK node kernel (proven R9, f32 states, inline RNG) -----
__global__ __launch_bounds__(256) void node_fb(
    int g0,
    const float* __restrict__ x, const float* __restrict__ edge_attr,
    const float* __restrict__ user_s,
    const float* __restrict__ W_msg, const float* __restrict__ b_msg,
    const float* __restrict__ W_edge, const float* __restrict__ b_edge,
    const float* __restrict__ W_self, const float* __restrict__ b_self,
    const float* __restrict__ W1, const float* __restrict__ b1,
    const int* __restrict__ src, const int* __restrict__ dst,
    float* __restrict__ states)
{
    const int g = g0 + blockIdx.x;
    const int tid = threadIdx.x;

    __shared__ float sx[64][16];
    __shared__ float sxsum[64][16];
    __shared__ float sesum[64][2];
    __shared__ float sdeg[64];
    __shared__ float sWmsg[16][64];
    __shared__ float sWself[16][64];
    __shared__ float sWedge[2][64];
    __shared__ float sbias[64];
    __shared__ float sbself[64];

    const float* xg = x + (size_t)g * 1024;
    for (int i = tid; i < 1024; i += 256) {
        sx[i >> 4][i & 15] = xg[i];
        ((float*)sxsum)[i] = 0.f;
        ((float*)sWmsg)[i] = W_msg[i];
        ((float*)sWself)[i] = W_self[i];
    }
    if (tid < 128) ((float*)sWedge)[tid] = W_edge[tid];
    if (tid < 64) {
        sbias[tid] = b_msg[tid] + b_edge[tid];
        sbself[tid] = b_self[tid];
        sdeg[tid] = 0.f;
        sesum[tid][0] = 0.f; sesum[tid][1] = 0.f;
    }
    __syncthreads();

    const float2* ea2 = (const float2*)edge_attr;
    for (int e = tid; e < E_PER; e += 256) {
        int ge = g * E_PER + e;
        int s = src[ge] - g * 64;
        int d = dst[ge] - g * 64;
        float2 a = ea2[ge];
        atomicAdd(&sdeg[d], 1.0f);
        atomicAdd(&sesum[d][0], a.x);
        atomicAdd(&sesum[d][1], a.y);
        #pragma unroll
        for (int k = 0; k < 16; ++k) atomicAdd(&sxsum[d][k], sx[s][k]);
    }
    __syncthreads();

    float* out = states + (size_t)blockIdx.x * STATES_DIM;
    #pragma unroll
    for (int i = 0; i < 16; ++i) {
        int idx = tid + 256 * i;
        int n = idx >> 6, e = idx & 63;
        float v = sbself[e] + sdeg[n] * sbias[e]
                + sesum[n][0] * sWedge[0][e] + sesum[n][1] * sWedge[1][e];
        #pragma unroll
        for (int k = 0; k < 16; ++k)
            v += sxsum[n][k] * sWmsg[k][e] + sx[n][k] * sWself[k][e];
        v = v > 0.f ? v : 0.f;
        v = keep_bit((uint32_t)g * 4096u + (uint32_t)idx) ? v * 2.0f : 0.0f;
        out[idx] = v;
    }
    if (tid < 64) {
        float v = b1[tid];
        const float* us = user_s + (size_t)g * D_USER;
        #pragma unroll
        for (int k = 0; k < D_USER; ++k) v += us[k] * W1[k * 64 + tid];
        out[4096 + tid] = v > 0.f ? v : 0.f;
    }
}

// ------------- W2 [4160,512] f32 -> W2T [512,4160] bf16 ---------------------
__global__ __launch_bounds__(256) void transpose_w2(const float* __restrict__ W2,
                                                    u16* __restrict__ W2T) {
    __shared__ float sT[32][33];
    const int k0 = blockIdx.x * 32, n0 = blockIdx.y * 32;
    const int tr = threadIdx.x >> 5, tc = threadIdx.x & 31;
    #pragma unroll
    for (int i = 0; i < 32; i += 8)
        sT[tr + i][tc] = W2[(size_t)(k0 + tr + i) * 512 + n0 + tc];
    __syncthreads();
    #pragma unroll
    for (int i = 0; i < 32; i += 8)
        W2T[(size_t)(n0 + tr + i) * GK + k0 + tc] = f2bf(sT[tc][tr + i]);
}

// ------------- gemm1 MFMA: h2 = relu(states @ W2 + b2) ----------------------
// BK=64, 8 mfma/iter, register prefetch pipeline (hide global latency).
// Layouts verified by R10 pass: A fr: m=lane&15,k=q*8+j; C/D: col=lane&15,
// row=q*4+reg.
__global__ __launch_bounds__(256) void gemm1_mfma(
    const u16* __restrict__ A, const u16* __restrict__ BT,
    const float* __restrict__ bias, u16* __restrict__ C)
{
    __shared__ u16 sA[64][72];     // 144 B rows (16B-divisible); 2-way banks
    __shared__ u16 sB[64][72];

    const int tid = threadIdx.x;
    const int m0 = blockIdx.x * 64, n0 = blockIdx.y * 64;
    const int wave = tid >> 6, lane = tid & 63;
    const int wm = (wave >> 1) * 32, wn = (wave & 1) * 32;
    const int lm = lane & 15, q = lane >> 4;

    f32x4 acc[2][2];
    #pragma unroll
    for (int i = 0; i < 2; ++i)
        #pragma unroll
        for (int j = 0; j < 2; ++j)
            #pragma unroll
            for (int r = 0; r < 4; ++r) acc[i][j][r] = 0.f;

    const int row = tid >> 2;          // 0..63
    const int seg = (tid & 3) * 16;    // 0,16,32,48

    const u16* pa = &A [(size_t)(m0 + row) * GK + seg];
    const u16* pb = &BT[(size_t)(n0 + row) * GK + seg];
    uint4 ra0 = *(const uint4*)pa,       ra1 = *(const uint4*)(pa + 8);
    uint4 rb0 = *(const uint4*)pb,       rb1 = *(const uint4*)(pb + 8);

    for (int k0 = 0; k0 < GK; k0 += 64) {
        __syncthreads();               // prev iter's LDS reads done
        *(uint4*)&sA[row][seg]     = ra0;
        *(uint4*)&sA[row][seg + 8] = ra1;
        *(uint4*)&sB[row][seg]     = rb0;
        *(uint4*)&sB[row][seg + 8] = rb1;
        __syncthreads();
        if (k0 + 64 < GK) {            // prefetch next tiles (overlaps MFMA)
            pa += 64; pb += 64;
            ra0 = *(const uint4*)pa;       ra1 = *(const uint4*)(pa + 8);
            rb0 = *(const uint4*)pb;       rb1 = *(const uint4*)(pb + 8);
        }
        #pragma unroll
        for (int kh = 0; kh < 2; ++kh) {
            short8 a0 = *(const short8*)&sA[wm + lm][kh * 32 + q * 8];
            short8 a1 = *(const short8*)&sA[wm + 16 + lm][kh * 32 + q * 8];
            short8 b0 = *(const short8*)&sB[wn + lm][kh * 32 + q * 8];
            short8 b1 = *(const short8*)&sB[wn + 16 + lm][kh * 32 + q * 8];
            acc[0][0] = __builtin_amdgcn_mfma_f32_16x16x32_bf16(a0, b0, acc[0][0], 0, 0, 0);
            acc[0][1] = __builtin_amdgcn_mfma_f32_16x16x32_bf16(a0, b1, acc[0][1], 0, 0, 0);
            acc[1][0] = __builtin_amdgcn_mfma_f32_16x16x32_bf16(a1, b0, acc[1][0], 0, 0, 0);
            acc[1][1] = __builtin_amdgcn_mfma_f32_16x16x32_bf16(a1, b1, acc[1][1], 0, 0, 0);
        }
    }

    #pragma unroll
    for (int mi = 0; mi < 2; ++mi)
        #pragma unroll
        for (int ni = 0; ni < 2; ++ni)
            #pragma unroll
            for (int r = 0; r < 4; ++r) {
                int m = m0 + wm + mi * 16 + q * 4 + r;
                int n = n0 + wn + ni * 16 + lm;
                float v = acc[mi][ni][r] + bias[n];
                v = v > 0.f ? v : 0.f;
                C[(size_t)m * 512 + n] = f2bf(v);
            }
}

// ------------- f32 GEMM (proven): C = act(A @ B + bias) ---------------------
template<typename AT, typename CT, bool RELU>
__global__ __launch_bounds__(256) void gemm_any(
    const AT* __restrict__ A, const float* __restrict__ B,
    const float* __restrict__ bias, CT* __restrict__ C,
    int M, int N, int K)
{
    __shared__ float sA[32][72];
    __shared__ float sB[32][64];

    const int tid = threadIdx.x;
    const int tx = tid & 15;
    const int ty = tid >> 4;
    const int m0 = blockIdx.x * 64, n0 = blockIdx.y * 64;

    float acc[4][4] = {};

    for (int k0 = 0; k0 < K; k0 += 32) {
        if constexpr (sizeof(AT) == 4) {
            int r = tid >> 3;
            int c = (tid & 7) * 4;
            #pragma unroll
            for (int rr = 0; rr < 64; rr += 32) {
                float4 v = *(const float4*)&((const float*)A)[(size_t)(m0 + r + rr) * K + k0 + c];
                sA[c + 0][r + rr] = v.x; sA[c + 1][r + rr] = v.y;
                sA[c + 2][r + rr] = v.z; sA[c + 3][r + rr] = v.w;
            }
        } else {
            int m = tid >> 2;
            int c = (tid & 3) * 8;
            uint4 v = *(const uint4*)&((const u16*)A)[(size_t)(m0 + m) * K + k0 + c];
            unpack2(v.x, sA[c + 0][m], sA[c + 1][m]);
            unpack2(v.y, sA[c + 2][m], sA[c + 3][m]);
            unpack2(v.z, sA[c + 4][m], sA[c + 5][m]);
            unpack2(v.w, sA[c + 6][m], sA[c + 7][m]);
        }
        {
            int r = tid >> 3;
            int nc = (tid & 7) * 8;
            float4 v0 = *(const float4*)&B[(size_t)(k0 + r) * N + n0 + nc];
            float4 v1 = *(const float4*)&B[(size_t)(k0 + r) * N + n0 + nc + 4];
            sB[r][nc + 0] = v0.x; sB[r][nc + 1] = v0.y;
            sB[r][nc + 2] = v0.z; sB[r][nc + 3] = v0.w;
            sB[r][nc + 4] = v1.x; sB[r][nc + 5] = v1.y;
            sB[r][nc + 6] = v1.z; sB[r][nc + 7] = v1.w;
        }
        __syncthreads();
        #pragma unroll
        for (int kk = 0; kk < 32; ++kk) {
            float4 av = *(const float4*)&sA[kk][ty * 4];
            float4 bv = *(const float4*)&sB[kk][tx * 4];
            float a_[4] = {av.x, av.y, av.z, av.w};
            float b_[4] = {bv.x, bv.y, bv.z, bv.w};
            #pragma unroll
            for (int i = 0; i < 4; ++i)
                #pragma unroll
                for (int j = 0; j < 4; ++j)
                    acc[i][j] += a_[i] * b_[j];
        }
        __syncthreads();
    }

    #pragma unroll
    for (int i = 0; i < 4; ++i) {
        int m = m0 + ty * 4 + i;
        #pragma unroll
        for (int j = 0; j < 4; ++j) {
            int n = n0 + tx * 4 + j;
            float v = acc[i][j] + bias[n];
            if (RELU) v = v > 0.f ? v : 0.f;
            if constexpr (sizeof(CT) == 2) C[(size_t)m * N + n] = (CT)f2bf(v);
            else                           C[(size_t)m * N + n] = (CT)v;
        }
    }
}

// ------------- softmax over axis 0 ------------------------------------------
__global__ __launch_bounds__(256) void softmax_kernel(
    const float* __restrict__ logits, float* __restrict__ out)
{
    const int n = blockIdx.x;
    const int tid = threadIdx.x;
    __shared__ float sred[4];
    const int wid = tid >> 6, lane = tid & 63;

    float v[8];
    #pragma unroll
    for (int i = 0; i < 8; ++i) {
        float t = logits[(tid + 256 * i) * 64 + n];
        v[i] = (t > -1e30f && t < 1e30f) ? t : 0.0f;
    }

    float mx = -3.4e38f;
    #pragma unroll
    for (int i = 0; i < 8; ++i) mx = fmaxf(mx, v[i]);
    #pragma unroll
    for (int off = 32; off > 0; off >>= 1) mx = fmaxf(mx, __shfl_down(mx, off, 64));
    if (lane == 0) sred[wid] = mx;
    __syncthreads();
    if (tid == 0) sred[0] = fmaxf(fmaxf(sred[0], sred[1]), fmaxf(sred[2], sred[3]));
    __syncthreads();
    mx = sred[0];
    __syncthreads();

    float sum = 0.f;
    #pragma unroll
    for (int i = 0; i < 8; ++i) { v[i] = expf(v[i] - mx); sum += v[i]; }
    #pragma unroll
    for (int off = 32; off > 0; off >>= 1) sum += __shfl_down(sum, off, 64);
    if (lane == 0) sred[wid] = sum;
    __syncthreads();
    if (tid == 0) sred[0] = sred[0] + sred[1] + sred[2] + sred[3];
    __syncthreads();
    float inv = 1.0f / sred[0];
    #pragma unroll
    for (int i = 0; i < 8; ++i) out[(tid + 256 * i) * 64 + n] = v[i] * inv;
}

// ---------------------------------------------------------------------------
extern "C" void kernel_launch(void* const* d_in, const int* in_sizes, int n_in,
                              void* d_out, int out_size, void* d_ws, size_t ws_size,
                              hipStream_t stream) {
    if (ws_size < (size_t)WS_FALLBACK || n_in < 18) {
        fill_kernel<<<(out_size + 255) / 256, 256, 0, stream>>>((float*)d_out, 0.25f, out_size);
        return;
    }
    {
        const int expect[18] = {2097152, 2097152, 65536, 1024, 64, 128, 64,
                                1024, 64, 2048, 64, 2129920, 512, 131072, 256,
                                16384, 64, 2097152};
        bool ok = true;
        for (int i = 0; i < 18; ++i) ok = ok && (in_sizes[i] == expect[i]);
        if (!ok || out_size != 131072) {
            fill_kernel<<<(out_size + 255) / 256, 256, 0, stream>>>((float*)d_out, 0.125f, out_size);
            return;
        }
    }

    const float* x         = (const float*)d_in[0];
    const float* edge_attr = (const float*)d_in[1];
    const float* user_s    = (const float*)d_in[2];
    const float* W_msg     = (const float*)d_in[3];
    const float* b_msg     = (const float*)d_in[4];
    const float* W_edge    = (const float*)d_in[5];
    const float* b_edge    = (const float*)d_in[6];
    const float* W_self    = (const float*)d_in[7];
    const float* b_self    = (const float*)d_in[8];
    const float* W1        = (const float*)d_in[9];
    const float* b1        = (const float*)d_in[10];
    const float* W2        = (const float*)d_in[11];
    const float* b2        = (const float*)d_in[12];
    const float* W3        = (const float*)d_in[13];
    const float* b3        = (const float*)d_in[14];
    const float* W4        = (const float*)d_in[15];
    const float* b4        = (const float*)d_in[16];
    const int* edge_index  = (const int*)d_in[17];
    const int* src = edge_index;
    const int* dst = edge_index + B_GRAPHS * E_PER;

    float* logits = (float*)d_out;     // gemm3 -> d_out, softmax in-place
    char* ws = (char*)d_ws;

    if (ws_size >= (size_t)WS_FAST) {
        // FAST layout (peak 23,396,352 = WS_FAST):
        //   states bf16 : [0,          17,039,360)
        //   mask u64    : [17,039,360, 18,087,936)   dead after node_fast
        //   W2T bf16    : [17,039,360, 21,299,200)   written AFTER node_fast
        //   h2 bf16     : [21,299,200, 23,396,352)
        //   h3 f32      : [0,           2,097,152)   overlay; states dead
        u16*   states = (u16*)ws;
        unsigned long long* mask = (unsigned long long*)(ws + 17039360);
        u16*   W2T    = (u16*)(ws + 17039360);
        u16*   h2     = (u16*)(ws + 21299200);
        float* h3     = (float*)ws;

        mask_kernel<<<32768, 256, 0, stream>>>(mask);
        node_fast<<<B_GRAPHS, 256, 0, stream>>>(
            x, edge_attr, user_s, W_msg, b_msg, W_edge, b_edge,
            W_self, b_self, W1, b1, src, dst, mask, states);
        transpose_w2<<<dim3(130, 16), 256, 0, stream>>>(W2, W2T);
        gemm1_mfma<<<dim3(32, 8), 256, 0, stream>>>(states, W2T, b2, h2);
        gemm_any<u16,   float, true ><<<dim3(32, 4), 256, 0, stream>>>(
            h2, W3, b3, h3, B_GRAPHS, HID / 2, HID);
        gemm_any<float, float, false><<<dim3(32, 1), 256, 0, stream>>>(
            h3, W4, b4, logits, B_GRAPHS, 64, HID / 2);
        softmax_kernel<<<64, 256, 0, stream>>>(logits, logits);
    } else {
        // FALLBACK (proven R9):
        float* states = (float*)ws;
        float* h3     = (float*)ws;
        u16*   h2     = (u16*)(ws + 4259840);

        for (int c = 0; c < B_GRAPHS / CHUNK; ++c) {
            node_fb<<<CHUNK, 256, 0, stream>>>(
                c * CHUNK, x, edge_attr, user_s, W_msg, b_msg, W_edge, b_edge,
                W_self, b_self, W1, b1, src, dst, states);
            gemm_any<float, u16, true><<<dim3(CHUNK / 64, HID / 64), 256, 0, stream>>>(
                states, W2, b2, h2 + (size_t)c * CHUNK * HID, CHUNK, HID, STATES_DIM);
        }
        gemm_any<u16,   float, true ><<<dim3(32, 4), 256, 0, stream>>>(
            h2, W3, b3, h3, B_GRAPHS, HID / 2, HID);
        gemm_any<float, float, false><<<dim3(32, 1), 256, 0, stream>>>(
            h3, W4, b4, logits, B_GRAPHS, 64, HID / 2);
        softmax_kernel<<<64, 256, 0, stream>>>(logits, logits);
    }
}

// Round 12
// 234.387 us; speedup vs baseline: 8.0524x; 1.3581x over previous
//
#include <hip/hip_runtime.h>
#include <stdint.h>

#define B_GRAPHS 2048
#define CHUNK 256                    // fallback path: graphs per chunk
#define E_PER 512
#define D_USER 32
#define HID 512
#define GK 4160                      // states dim = 64*64 + 64
#define STATES_DIM 4160
#define WS_FALLBACK 6356992
#define WS_FAST 23396352

typedef unsigned short u16;
typedef unsigned int u32;
typedef __attribute__((ext_vector_type(8))) short short8;   // 8 bf16 (4 VGPRs)
typedef __attribute__((ext_vector_type(4))) float f32x4;    // MFMA accumulator

// ---------------- bf16 helpers ----------------------------------------------
__device__ __forceinline__ float bf2f(u16 b) {
    union { uint32_t u; float f; } c; c.u = ((uint32_t)b) << 16; return c.f;
}
__device__ __forceinline__ u16 f2bf(float f) {   // round-to-nearest-even
    union { float f; uint32_t u; } c; c.f = f;
    uint32_t u = c.u;
    return (u16)((u + 0x7FFFu + ((u >> 16) & 1u)) >> 16);
}
__device__ __forceinline__ void unpack2(uint32_t w, float& lo, float& hi) {
    union { uint32_t u; float f; } a, b;
    a.u = w << 16; b.u = w & 0xFFFF0000u;
    lo = a.f; hi = b.f;
}

// ---------------- threefry2x32, key=(0,42), partitionable (proven R9) -------
__device__ __forceinline__ uint32_t rotl32(uint32_t v, int r) {
    return (v << r) | (v >> (32 - r));
}
__device__ __forceinline__ void threefry_0_42(uint32_t x0, uint32_t x1,
                                              uint32_t& o0, uint32_t& o1) {
    const uint32_t ks0 = 0u, ks1 = 42u, ks2 = 0x1BD11BDAu ^ 42u;
    x0 += ks0; x1 += ks1;
#define TFR(r) { x0 += x1; x1 = rotl32(x1, (r)); x1 ^= x0; }
    TFR(13) TFR(15) TFR(26) TFR(6)
    x0 += ks1; x1 += ks2 + 1u;
    TFR(17) TFR(29) TFR(16) TFR(24)
    x0 += ks2; x1 += ks0 + 2u;
    TFR(13) TFR(15) TFR(26) TFR(6)
    x0 += ks0; x1 += ks1 + 3u;
    TFR(17) TFR(29) TFR(16) TFR(24)
    x0 += ks1; x1 += ks2 + 4u;
    TFR(13) TFR(15) TFR(26) TFR(6)
    x0 += ks2; x1 += ks0 + 5u;
#undef TFR
    o0 = x0; o1 = x1;
}
__device__ __forceinline__ bool keep_bit(uint32_t j) {
    uint32_t o0, o1;
    threefry_0_42(0u, j, o0, o1);
    return (((o0 ^ o1) >> 31) == 0u);
}

// ------------- mask kernel: 64 keep-bits per u64 word -----------------------
__global__ __launch_bounds__(256) void mask_kernel(unsigned long long* __restrict__ mask) {
    uint32_t j = blockIdx.x * 256u + threadIdx.x;    // 0 .. 8388607
    uint32_t o0, o1;
    threefry_0_42(0u, j, o0, o1);
    unsigned long long b = __ballot(((o0 ^ o1) >> 31) == 0u);
    if ((threadIdx.x & 63u) == 0u) mask[j >> 6] = b;
}

// ------------- diagnostic fill ----------------------------------------------
__global__ __launch_bounds__(256) void fill_kernel(float* __restrict__ out, float v, int n) {
    int i = blockIdx.x * 256 + threadIdx.x;
    if (i < n) out[i] = v;
}

// ------------- FAST node kernel: dense-adjacency aggregation ----------------
// Per edge: 1 u32 count atomic (bank d%32 ~2-way) + 2 esum atomics, instead of
// 19 atomics with 32-way conflicts. Then sxsum = cnt^T @ x densely; deg = row
// sums for free.
__global__ __launch_bounds__(256) void node_fast(
    const float* __restrict__ x, const float* __restrict__ edge_attr,
    const float* __restrict__ user_s,
    const float* __restrict__ W_msg, const float* __restrict__ b_msg,
    const float* __restrict__ W_edge, const float* __restrict__ b_edge,
    const float* __restrict__ W_self, const float* __restrict__ b_self,
    const float* __restrict__ W1, const float* __restrict__ b1,
    const int* __restrict__ src, const int* __restrict__ dst,
    const unsigned long long* __restrict__ mask,
    u16* __restrict__ states)
{
    const int g = blockIdx.x;
    const int tid = threadIdx.x;
    const int w = tid >> 6, lane = tid & 63;

    __shared__ float sx[64][16];       // [s][k]
    __shared__ u32   scnt[64][64];     // [s][d]  adjacency counts
    __shared__ float sxsum[64][16];    // [d][k]
    __shared__ float sesum[2][64];     // [j][d]
    __shared__ float sdeg[64];
    __shared__ unsigned long long smask[64];

    // per-lane weight columns in registers (coalesced loads)
    float rWmsg[16], rWself[16];
    #pragma unroll
    for (int k = 0; k < 16; ++k) {
        rWmsg[k]  = W_msg[k * 64 + lane];
        rWself[k] = W_self[k * 64 + lane];
    }
    const float rWe0   = W_edge[lane];
    const float rWe1   = W_edge[64 + lane];
    const float rbias  = b_msg[lane] + b_edge[lane];
    const float rbself = b_self[lane];

    const float* xg = x + (size_t)g * 1024;
    for (int i = tid; i < 1024; i += 256) ((float*)sx)[i] = xg[i];
    {   // zero scnt (4096 words, 16/thread, consecutive banks)
        uint4 z = make_uint4(0, 0, 0, 0);
        u32* c0 = &scnt[0][0] + tid * 16;
        *(uint4*)(c0 + 0)  = z; *(uint4*)(c0 + 4)  = z;
        *(uint4*)(c0 + 8)  = z; *(uint4*)(c0 + 12) = z;
    }
    if (tid < 64) {
        sesum[0][tid] = 0.f; sesum[1][tid] = 0.f;
        smask[tid] = mask[g * 64 + tid];
    }
    __syncthreads();

    const float2* ea2 = (const float2*)edge_attr;
    for (int e = tid; e < E_PER; e += 256) {
        int ge = g * E_PER + e;
        int s = src[ge] - g * 64;
        int d = dst[ge] - g * 64;
        float2 a = ea2[ge];
        atomicAdd(&scnt[s][d], 1u);
        atomicAdd(&sesum[0][d], a.x);
        atomicAdd(&sesum[1][d], a.y);
    }
    __syncthreads();

    {   // dense MAC: sxsum[d][kg*4..+3] = sum_s cnt[s][d] * x[s][kg*4..+3]
        const int d = tid >> 2, kg = tid & 3;
        float4 acc = make_float4(0.f, 0.f, 0.f, 0.f);
        float dg = 0.f;
        #pragma unroll 8
        for (int s = 0; s < 64; ++s) {
            float c = (float)scnt[s][d];
            dg += c;
            float4 xv = *(const float4*)&sx[s][kg * 4];
            acc.x += c * xv.x; acc.y += c * xv.y;
            acc.z += c * xv.z; acc.w += c * xv.w;
        }
        *(float4*)&sxsum[d][kg * 4] = acc;
        if (kg == 0) sdeg[d] = dg;
    }
    __syncthreads();

    u16* out = states + (size_t)g * STATES_DIM;
    #pragma unroll
    for (int i = 0; i < 16; ++i) {
        const int n = 4 * i + w;                       // wave-uniform node
        float v = rbself + sdeg[n] * rbias
                + sesum[0][n] * rWe0 + sesum[1][n] * rWe1;
        float4 s0 = *(const float4*)&sxsum[n][0];
        float4 s1 = *(const float4*)&sxsum[n][4];
        float4 s2 = *(const float4*)&sxsum[n][8];
        float4 s3 = *(const float4*)&sxsum[n][12];
        float4 x0 = *(const float4*)&sx[n][0];
        float4 x1 = *(const float4*)&sx[n][4];
        float4 x2 = *(const float4*)&sx[n][8];
        float4 x3 = *(const float4*)&sx[n][12];
        v += s0.x*rWmsg[0]  + s0.y*rWmsg[1]  + s0.z*rWmsg[2]  + s0.w*rWmsg[3]
           + s1.x*rWmsg[4]  + s1.y*rWmsg[5]  + s1.z*rWmsg[6]  + s1.w*rWmsg[7]
           + s2.x*rWmsg[8]  + s2.y*rWmsg[9]  + s2.z*rWmsg[10] + s2.w*rWmsg[11]
           + s3.x*rWmsg[12] + s3.y*rWmsg[13] + s3.z*rWmsg[14] + s3.w*rWmsg[15]
           + x0.x*rWself[0]  + x0.y*rWself[1]  + x0.z*rWself[2]  + x0.w*rWself[3]
           + x1.x*rWself[4]  + x1.y*rWself[5]  + x1.z*rWself[6]  + x1.w*rWself[7]
           + x2.x*rWself[8]  + x2.y*rWself[9]  + x2.z*rWself[10] + x2.w*rWself[11]
           + x3.x*rWself[12] + x3.y*rWself[13] + x3.z*rWself[14] + x3.w*rWself[15];
        v = v > 0.f ? v : 0.f;                         // relu
        unsigned long long m = smask[n];
        v = ((m >> lane) & 1ull) ? v * 2.0f : 0.0f;    // dropout p=0.5
        out[n * 64 + lane] = f2bf(v);
    }
    if (tid < 64) {                                    // user = relu(u @ W1 + b1)
        float v = b1[tid];
        const float* us = user_s + (size_t)g * D_USER;
        #pragma unroll
        for (int k = 0; k < D_USER; ++k) v += us[k] * W1[k * 64 + tid];
        out[4096 + tid] = f2bf(v > 0.f ? v : 0.f);
    }
}

// ------------- FALLBACK node kernel (proven R9) -----------------------------
__global__ __launch_bounds__(256) void node_fb(
    int g0,
    const float* __restrict__ x, const float* __restrict__ edge_attr,
    const float* __restrict__ user_s,
    const float* __restrict__ W_msg, const float* __restrict__ b_msg,
    const float* __restrict__ W_edge, const float* __restrict__ b_edge,
    const float* __restrict__ W_self, const float* __restrict__ b_self,
    const float* __restrict__ W1, const float* __restrict__ b1,
    const int* __restrict__ src, const int* __restrict__ dst,
    float* __restrict__ states)
{
    const int g = g0 + blockIdx.x;
    const int tid = threadIdx.x;

    __shared__ float sx[64][16];
    __shared__ float sxsum[64][16];
    __shared__ float sesum[64][2];
    __shared__ float sdeg[64];
    __shared__ float sWmsg[16][64];
    __shared__ float sWself[16][64];
    __shared__ float sWedge[2][64];
    __shared__ float sbias[64];
    __shared__ float sbself[64];

    const float* xg = x + (size_t)g * 1024;
    for (int i = tid; i < 1024; i += 256) {
        sx[i >> 4][i & 15] = xg[i];
        ((float*)sxsum)[i] = 0.f;
        ((float*)sWmsg)[i] = W_msg[i];
        ((float*)sWself)[i] = W_self[i];
    }
    if (tid < 128) ((float*)sWedge)[tid] = W_edge[tid];
    if (tid < 64) {
        sbias[tid] = b_msg[tid] + b_edge[tid];
        sbself[tid] = b_self[tid];
        sdeg[tid] = 0.f;
        sesum[tid][0] = 0.f; sesum[tid][1] = 0.f;
    }
    __syncthreads();

    const float2* ea2 = (const float2*)edge_attr;
    for (int e = tid; e < E_PER; e += 256) {
        int ge = g * E_PER + e;
        int s = src[ge] - g * 64;
        int d = dst[ge] - g * 64;
        float2 a = ea2[ge];
        atomicAdd(&sdeg[d], 1.0f);
        atomicAdd(&sesum[d][0], a.x);
        atomicAdd(&sesum[d][1], a.y);
        #pragma unroll
        for (int k = 0; k < 16; ++k) atomicAdd(&sxsum[d][k], sx[s][k]);
    }
    __syncthreads();

    float* out = states + (size_t)blockIdx.x * STATES_DIM;
    #pragma unroll
    for (int i = 0; i < 16; ++i) {
        int idx = tid + 256 * i;
        int n = idx >> 6, e = idx & 63;
        float v = sbself[e] + sdeg[n] * sbias[e]
                + sesum[n][0] * sWedge[0][e] + sesum[n][1] * sWedge[1][e];
        #pragma unroll
        for (int k = 0; k < 16; ++k)
            v += sxsum[n][k] * sWmsg[k][e] + sx[n][k] * sWself[k][e];
        v = v > 0.f ? v : 0.f;
        v = keep_bit((uint32_t)g * 4096u + (uint32_t)idx) ? v * 2.0f : 0.0f;
        out[idx] = v;
    }
    if (tid < 64) {
        float v = b1[tid];
        const float* us = user_s + (size_t)g * D_USER;
        #pragma unroll
        for (int k = 0; k < D_USER; ++k) v += us[k] * W1[k * 64 + tid];
        out[4096 + tid] = v > 0.f ? v : 0.f;
    }
}

// ------------- W2 [4160,512] f32 -> W2T [512,4160] bf16 ---------------------
__global__ __launch_bounds__(256) void transpose_w2(const float* __restrict__ W2,
                                                    u16* __restrict__ W2T) {
    __shared__ float sT[32][33];
    const int k0 = blockIdx.x * 32, n0 = blockIdx.y * 32;
    const int tr = threadIdx.x >> 5, tc = threadIdx.x & 31;
    #pragma unroll
    for (int i = 0; i < 32; i += 8)
        sT[tr + i][tc] = W2[(size_t)(k0 + tr + i) * 512 + n0 + tc];
    __syncthreads();
    #pragma unroll
    for (int i = 0; i < 32; i += 8)
        W2T[(size_t)(n0 + tr + i) * GK + k0 + tc] = f2bf(sT[tc][tr + i]);
}

// ------------- gemm1 MFMA: h2 = relu(states @ W2 + b2) ----------------------
// 32x64 tiles -> 512 blocks (2/CU, latency overlap). XCD swizzle: bid&7 = xcd
// owns 8 consecutive m-tiles -> per-XCD A working set 2.1 MB (fits 4 MB L2).
// Fragment layouts R10-verified.
__global__ __launch_bounds__(256) void gemm1_mfma(
    const u16* __restrict__ A, const u16* __restrict__ BT,
    const float* __restrict__ bias, u16* __restrict__ C)
{
    const int bid = blockIdx.x;
    const int j = bid >> 3;
    const int mt = (bid & 7) * 8 + (j & 7);   // 0..63
    const int nt = j >> 3;                    // 0..7
    const int m0 = mt * 32, n0 = nt * 64;

    __shared__ u16 sA[32][72];     // 144 B rows
    __shared__ u16 sB[64][72];

    const int tid = threadIdx.x;
    const int wave = tid >> 6, lane = tid & 63;
    const int wm = (wave & 1) * 16, wn = (wave >> 1) * 32;
    const int lm = lane & 15, q = lane >> 4;

    f32x4 acc[2];
    #pragma unroll
    for (int i = 0; i < 2; ++i)
        #pragma unroll
        for (int r = 0; r < 4; ++r) acc[i][r] = 0.f;

    const int arow = tid >> 3, aseg = (tid & 7) * 8;    // 32 rows x 8 segs
    const int brow = tid >> 2, bseg = (tid & 3) * 16;   // 64 rows x 4 segs

    const u16* pa = &A [(size_t)(m0 + arow) * GK + aseg];
    const u16* pb = &BT[(size_t)(n0 + brow) * GK + bseg];
    uint4 ra  = *(const uint4*)pa;
    uint4 rb0 = *(const uint4*)pb, rb1 = *(const uint4*)(pb + 8);

    for (int k0 = 0; k0 < GK; k0 += 64) {
        __syncthreads();
        *(uint4*)&sA[arow][aseg]     = ra;
        *(uint4*)&sB[brow][bseg]     = rb0;
        *(uint4*)&sB[brow][bseg + 8] = rb1;
        __syncthreads();
        if (k0 + 64 < GK) {
            pa += 64; pb += 64;
            ra  = *(const uint4*)pa;
            rb0 = *(const uint4*)pb; rb1 = *(const uint4*)(pb + 8);
        }
        #pragma unroll
        for (int kh = 0; kh < 2; ++kh) {
            short8 a  = *(const short8*)&sA[wm + lm][kh * 32 + q * 8];
            short8 b0 = *(const short8*)&sB[wn + lm][kh * 32 + q * 8];
            short8 b1 = *(const short8*)&sB[wn + 16 + lm][kh * 32 + q * 8];
            acc[0] = __builtin_amdgcn_mfma_f32_16x16x32_bf16(a, b0, acc[0], 0, 0, 0);
            acc[1] = __builtin_amdgcn_mfma_f32_16x16x32_bf16(a, b1, acc[1], 0, 0, 0);
        }
    }

    #pragma unroll
    for (int ni = 0; ni < 2; ++ni)
        #pragma unroll
        for (int r = 0; r < 4; ++r) {
            int m = m0 + wm + q * 4 + r;
            int n = n0 + wn + ni * 16 + lm;
            float v = acc[ni][r] + bias[n];
            v = v > 0.f ? v : 0.f;
            C[(size_t)m * 512 + n] = f2bf(v);
        }
}

// ------------- f32 GEMM (proven): C = act(A @ B + bias) ---------------------
template<typename AT, typename CT, bool RELU>
__global__ __launch_bounds__(256) void gemm_any(
    const AT* __restrict__ A, const float* __restrict__ B,
    const float* __restrict__ bias, CT* __restrict__ C,
    int M, int N, int K)
{
    __shared__ float sA[32][72];
    __shared__ float sB[32][64];

    const int tid = threadIdx.x;
    const int tx = tid & 15;
    const int ty = tid >> 4;
    const int m0 = blockIdx.x * 64, n0 = blockIdx.y * 64;

    float acc[4][4] = {};

    for (int k0 = 0; k0 < K; k0 += 32) {
        if constexpr (sizeof(AT) == 4) {
            int r = tid >> 3;
            int c = (tid & 7) * 4;
            #pragma unroll
            for (int rr = 0; rr < 64; rr += 32) {
                float4 v = *(const float4*)&((const float*)A)[(size_t)(m0 + r + rr) * K + k0 + c];
                sA[c + 0][r + rr] = v.x; sA[c + 1][r + rr] = v.y;
                sA[c + 2][r + rr] = v.z; sA[c + 3][r + rr] = v.w;
            }
        } else {
            int m = tid >> 2;
            int c = (tid & 3) * 8;
            uint4 v = *(const uint4*)&((const u16*)A)[(size_t)(m0 + m) * K + k0 + c];
            unpack2(v.x, sA[c + 0][m], sA[c + 1][m]);
            unpack2(v.y, sA[c + 2][m], sA[c + 3][m]);
            unpack2(v.z, sA[c + 4][m], sA[c + 5][m]);
            unpack2(v.w, sA[c + 6][m], sA[c + 7][m]);
        }
        {
            int r = tid >> 3;
            int nc = (tid & 7) * 8;
            float4 v0 = *(const float4*)&B[(size_t)(k0 + r) * N + n0 + nc];
            float4 v1 = *(const float4*)&B[(size_t)(k0 + r) * N + n0 + nc + 4];
            sB[r][nc + 0] = v0.x; sB[r][nc + 1] = v0.y;
            sB[r][nc + 2] = v0.z; sB[r][nc + 3] = v0.w;
            sB[r][nc + 4] = v1.x; sB[r][nc + 5] = v1.y;
            sB[r][nc + 6] = v1.z; sB[r][nc + 7] = v1.w;
        }
        __syncthreads();
        #pragma unroll
        for (int kk = 0; kk < 32; ++kk) {
            float4 av = *(const float4*)&sA[kk][ty * 4];
            float4 bv = *(const float4*)&sB[kk][tx * 4];
            float a_[4] = {av.x, av.y, av.z, av.w};
            float b_[4] = {bv.x, bv.y, bv.z, bv.w};
            #pragma unroll
            for (int i = 0; i < 4; ++i)
                #pragma unroll
                for (int j = 0; j < 4; ++j)
                    acc[i][j] += a_[i] * b_[j];
        }
        __syncthreads();
    }

    #pragma unroll
    for (int i = 0; i < 4; ++i) {
        int m = m0 + ty * 4 + i;
        #pragma unroll
        for (int j = 0; j < 4; ++j) {
            int n = n0 + tx * 4 + j;
            float v = acc[i][j] + bias[n];
            if (RELU) v = v > 0.f ? v : 0.f;
            if constexpr (sizeof(CT) == 2) C[(size_t)m * N + n] = (CT)f2bf(v);
            else                           C[(size_t)m * N + n] = (CT)v;
        }
    }
}

// ------------- softmax over axis 0 ------------------------------------------
__global__ __launch_bounds__(256) void softmax_kernel(
    const float* __restrict__ logits, float* __restrict__ out)
{
    const int n = blockIdx.x;
    const int tid = threadIdx.x;
    __shared__ float sred[4];
    const int wid = tid >> 6, lane = tid & 63;

    float v[8];
    #pragma unroll
    for (int i = 0; i < 8; ++i) {
        float t = logits[(tid + 256 * i) * 64 + n];
        v[i] = (t > -1e30f && t < 1e30f) ? t : 0.0f;
    }

    float mx = -3.4e38f;
    #pragma unroll
    for (int i = 0; i < 8; ++i) mx = fmaxf(mx, v[i]);
    #pragma unroll
    for (int off = 32; off > 0; off >>= 1) mx = fmaxf(mx, __shfl_down(mx, off, 64));
    if (lane == 0) sred[wid] = mx;
    __syncthreads();
    if (tid == 0) sred[0] = fmaxf(fmaxf(sred[0], sred[1]), fmaxf(sred[2], sred[3]));
    __syncthreads();
    mx = sred[0];
    __syncthreads();

    float sum = 0.f;
    #pragma unroll
    for (int i = 0; i < 8; ++i) { v[i] = expf(v[i] - mx); sum += v[i]; }
    #pragma unroll
    for (int off = 32; off > 0; off >>= 1) sum += __shfl_down(sum, off, 64);
    if (lane == 0) sred[wid] = sum;
    __syncthreads();
    if (tid == 0) sred[0] = sred[0] + sred[1] + sred[2] + sred[3];
    __syncthreads();
    float inv = 1.0f / sred[0];
    #pragma unroll
    for (int i = 0; i < 8; ++i) out[(tid + 256 * i) * 64 + n] = v[i] * inv;
}

// ---------------------------------------------------------------------------
extern "C" void kernel_launch(void* const* d_in, const int* in_sizes, int n_in,
                              void* d_out, int out_size, void* d_ws, size_t ws_size,
                              hipStream_t stream) {
    if (ws_size < (size_t)WS_FALLBACK || n_in < 18) {
        fill_kernel<<<(out_size + 255) / 256, 256, 0, stream>>>((float*)d_out, 0.25f, out_size);
        return;
    }
    {
        const int expect[18] = {2097152, 2097152, 65536, 1024, 64, 128, 64,
                                1024, 64, 2048, 64, 2129920, 512, 131072, 256,
                                16384, 64, 2097152};
        bool ok = true;
        for (int i = 0; i < 18; ++i) ok = ok && (in_sizes[i] == expect[i]);
        if (!ok || out_size != 131072) {
            fill_kernel<<<(out_size + 255) / 256, 256, 0, stream>>>((float*)d_out, 0.125f, out_size);
            return;
        }
    }

    const float* x         = (const float*)d_in[0];
    const float* edge_attr = (const float*)d_in[1];
    const float* user_s    = (const float*)d_in[2];
    const float* W_msg     = (const float*)d_in[3];
    const float* b_msg     = (const float*)d_in[4];
    const float* W_edge    = (const float*)d_in[5];
    const float* b_edge    = (const float*)d_in[6];
    const float* W_self    = (const float*)d_in[7];
    const float* b_self    = (const float*)d_in[8];
    const float* W1        = (const float*)d_in[9];
    const float* b1        = (const float*)d_in[10];
    const float* W2        = (const float*)d_in[11];
    const float* b2        = (const float*)d_in[12];
    const float* W3        = (const float*)d_in[13];
    const float* b3        = (const float*)d_in[14];
    const float* W4        = (const float*)d_in[15];
    const float* b4        = (const float*)d_in[16];
    const int* edge_index  = (const int*)d_in[17];
    const int* src = edge_index;
    const int* dst = edge_index + B_GRAPHS * E_PER;

    float* logits = (float*)d_out;     // gemm3 -> d_out, softmax in-place
    char* ws = (char*)d_ws;

    if (ws_size >= (size_t)WS_FAST) {
        // FAST layout (peak 23,396,352 = WS_FAST):
        //   states bf16 : [0,          17,039,360)
        //   mask u64    : [17,039,360, 18,087,936)   dead after node_fast
        //   W2T bf16    : [17,039,360, 21,299,200)   written AFTER node_fast
        //   h2 bf16     : [21,299,200, 23,396,352)
        //   h3 f32      : [0,           2,097,152)   overlay; states dead
        u16*   states = (u16*)ws;
        unsigned long long* mask = (unsigned long long*)(ws + 17039360);
        u16*   W2T    = (u16*)(ws + 17039360);
        u16*   h2     = (u16*)(ws + 21299200);
        float* h3     = (float*)ws;

        mask_kernel<<<32768, 256, 0, stream>>>(mask);
        node_fast<<<B_GRAPHS, 256, 0, stream>>>(
            x, edge_attr, user_s, W_msg, b_msg, W_edge, b_edge,
            W_self, b_self, W1, b1, src, dst, mask, states);
        transpose_w2<<<dim3(130, 16), 256, 0, stream>>>(W2, W2T);
        gemm1_mfma<<<512, 256, 0, stream>>>(states, W2T, b2, h2);
        gemm_any<u16,   float, true ><<<dim3(32, 4), 256, 0, stream>>>(
            h2, W3, b3, h3, B_GRAPHS, HID / 2, HID);
        gemm_any<float, float, false><<<dim3(32, 1), 256, 0, stream>>>(
            h3, W4, b4, logits, B_GRAPHS, 64, HID / 2);
        softmax_kernel<<<64, 256, 0, stream>>>(logits, logits);
    } else {
        // FALLBACK (proven R9):
        float* states = (float*)ws;
        float* h3     = (float*)ws;
        u16*   h2     = (u16*)(ws + 4259840);

        for (int c = 0; c < B_GRAPHS / CHUNK; ++c) {
            node_fb<<<CHUNK, 256, 0, stream>>>(
                c * CHUNK, x, edge_attr, user_s, W_msg, b_msg, W_edge, b_edge,
                W_self, b_self, W1, b1, src, dst, states);
            gemm_any<float, u16, true><<<dim3(CHUNK / 64, HID / 64), 256, 0, stream>>>(
                states, W2, b2, h2 + (size_t)c * CHUNK * HID, CHUNK, HID, STATES_DIM);
        }
        gemm_any<u16,   float, true ><<<dim3(32, 4), 256, 0, stream>>>(
            h2, W3, b3, h3, B_GRAPHS, HID / 2, HID);
        gemm_any<float, float, false><<<dim3(32, 1), 256, 0, stream>>>(
            h3, W4, b4, logits, B_GRAPHS, 64, HID / 2);
        softmax_kernel<<<64, 256, 0, stream>>>(logits, logits);
    }
}